// Round 4
// baseline (711.463 us; speedup 1.0000x reference)
//
#include <hip/hip_runtime.h>
#include <math.h>

// MoE: B=2 S=2048 D=1024 E=8 H=4096 K=2
#define Bc 2
#define Sc 2048
#define Dc 1024
#define Ec 8
#define Hc 4096
#define Tc (Bc*Sc)          // 4096 tokens
#define NSLOT (Tc*2)        // 8192 token-expert slots (top-2 always)
#define SLOTPAD 8448        // NSLOT + 256 slack rows (padded tile over-read)
#define FINAL_N ((size_t)Tc*Dc)
#define PROWS ((size_t)SLOTPAD*32)   // ushorts per K-panel (32-wide) of A/HH
#define NKT1 16             // GEMM1 K-tiles of 64 (Dc/64)
#define NKT2 64             // GEMM2 K-tiles of 64 (Hc/64)

typedef float f32x4 __attribute__((ext_vector_type(4)));
typedef __bf16 bf16x8 __attribute__((ext_vector_type(8)));

__device__ __forceinline__ unsigned short f2bf(float f) {
    union { float f; unsigned int u; } v; v.f = f;
    return (unsigned short)((v.u + 0x7fffu + ((v.u >> 16) & 1u)) >> 16);
}
__device__ __forceinline__ unsigned int pack2bf(float a, float b) {
    return (unsigned int)f2bf(a) | ((unsigned int)f2bf(b) << 16);
}

// async global->LDS, 16B per lane. LDS dest = uniform base + lane*16 (linear).
__device__ __forceinline__ void gload16(const unsigned short* g, unsigned short* l) {
    __builtin_amdgcn_global_load_lds(
        (const __attribute__((address_space(1))) unsigned int*)g,
        (__attribute__((address_space(3))) unsigned int*)l,
        16, 0, 0);
}

// raw barrier with compiler fences (NO vmcnt(0) drain, unlike __syncthreads)
__device__ __forceinline__ void fence_bar() {
    __builtin_amdgcn_sched_barrier(0);
    asm volatile("s_barrier" ::: "memory");
    __builtin_amdgcn_sched_barrier(0);
}

// ------- [R][C] fp32 -> panel-major bf16 [C/128][R/32][128][32], chunk-XOR pre-swizzled -------
__global__ void k_transpose_panel(const float* __restrict__ inA, const float* __restrict__ inB,
                                  unsigned short* __restrict__ outA, unsigned short* __restrict__ outB,
                                  int R, int C, int nz_per_mat) {
    __shared__ float tile[64][65];
    int z = blockIdx.z;
    const float* in; unsigned short* out;
    if (z < nz_per_mat) { in = inA; out = outA; }
    else { in = inB; out = outB; z -= nz_per_mat; }
    size_t zbase = (size_t)z * (size_t)R * C;
    int R32 = R >> 5;
    int cb = blockIdx.x * 64, rb = blockIdx.y * 64;
    int t = threadIdx.x;             // 256
    int q = t & 15, g = t >> 4;
    #pragma unroll
    for (int j = 0; j < 4; j++) {
        int row = g + 16*j;
        float4 v = *(const float4*)&in[zbase + (size_t)(rb+row)*C + cb + q*4];
        tile[row][q*4+0] = v.x; tile[row][q*4+1] = v.y;
        tile[row][q*4+2] = v.z; tile[row][q*4+3] = v.w;
    }
    __syncthreads();
    #pragma unroll
    for (int j = 0; j < 4; j++) {
        int co = g + 16*j;
        int c = cb + co;
        int r0 = rb + q*4;
        ushort4 o;
        o.x = f2bf(tile[q*4+0][co]); o.y = f2bf(tile[q*4+1][co]);
        o.z = f2bf(tile[q*4+2][co]); o.w = f2bf(tile[q*4+3][co]);
        int cr = c & 127;
        int ch = ((r0 >> 3) & 3) ^ ((cr >> 1) & 3);
        size_t off = zbase + (((size_t)(c >> 7) * R32 + (r0 >> 5)) * 4096)
                   + (size_t)cr * 32 + ch * 8 + (r0 & 7);
        *(ushort4*)&out[off] = o;
    }
}

// ---------------- gating: one wave per token ----------------
__global__ void k_gate(const float* __restrict__ x, const float* __restrict__ noise,
                       const float* __restrict__ Wg, const float* __restrict__ nw,
                       float* __restrict__ out_idx, int* __restrict__ counts,
                       int* __restrict__ tok_top, float* __restrict__ tok_w) {
    int t = blockIdx.x;
    int lane = threadIdx.x;                     // 64
    const float* xr = x + (size_t)t * Dc;
    double acc[Ec];
    #pragma unroll
    for (int e = 0; e < Ec; e++) acc[e] = 0.0;
    for (int i = 0; i < Dc/64; i++) {
        int d = lane + i*64;
        double xv = (double)xr[d];
        #pragma unroll
        for (int e = 0; e < Ec; e++) acc[e] += xv * (double)Wg[e*Dc + d];
    }
    #pragma unroll
    for (int e = 0; e < Ec; e++)
        for (int off = 32; off > 0; off >>= 1)
            acc[e] += __shfl_down(acc[e], off);
    if (lane == 0) {
        double noisy[Ec];
        #pragma unroll
        for (int e = 0; e < Ec; e++)
            noisy[e] = acc[e] + (double)noise[t*Ec + e] * (double)nw[e];
        int i0 = 0;
        for (int e = 1; e < Ec; e++) if (noisy[e] > noisy[i0]) i0 = e;   // ties -> lowest idx
        int i1 = -1;
        for (int e = 0; e < Ec; e++) {
            if (e == i0) continue;
            if (i1 < 0 || noisy[e] > noisy[i1]) i1 = e;
        }
        double ee = exp(noisy[i1] - noisy[i0]);   // v1 <= v0, stable
        float w0 = (float)(1.0 / (1.0 + ee));
        float w1 = (float)(ee / (1.0 + ee));
        out_idx[t*2 + 0] = (float)i0;
        out_idx[t*2 + 1] = (float)i1;
        tok_top[t*2] = i0; tok_top[t*2+1] = i1;
        tok_w[t*2] = w0;   tok_w[t*2+1] = w1;
        atomicAdd(&counts[i0], 1);
        atomicAdd(&counts[i1], 1);
    }
}

__global__ void k_scan(const int* __restrict__ counts, int* __restrict__ offsets) {
    if (threadIdx.x == 0) {
        int s = 0;
        for (int e = 0; e < Ec; e++) { offsets[e] = s; s += counts[e]; }
        offsets[Ec] = s;
    }
}

__global__ void k_fill(const int* __restrict__ tok_top, const int* __restrict__ offsets,
                       int* __restrict__ fill, int* __restrict__ slot_token,
                       int* __restrict__ slot_of, int* __restrict__ slot_pos) {
    int t = blockIdx.x * 256 + threadIdx.x;
    if (t >= Tc) return;
    #pragma unroll
    for (int j = 0; j < 2; j++) {
        int e = tok_top[t*2 + j];
        int pos = atomicAdd(&fill[e], 1);
        int slot = offsets[e] + pos;
        slot_token[slot] = t;
        slot_of[t*2 + j] = slot;
        slot_pos[slot] = pos;                 // expert-local row (swizzle key source)
    }
}

// ---- pack A: gather + cvt into K-panel-major APK[kp=32][SLOTPAD][32], pre-swizzled ----
__global__ void k_packA(const float* __restrict__ x, const int* __restrict__ slot_token,
                        const int* __restrict__ slot_pos, unsigned short* __restrict__ apk) {
    int s = blockIdx.x * 4 + (threadIdx.x >> 6);
    int lane = threadIdx.x & 63;
    int token = slot_token[s];
    int pos = slot_pos[s];
    const float4* px = (const float4*)(x + (size_t)token * Dc) + lane*4;
    float4 v0 = px[0], v1 = px[1], v2 = px[2], v3 = px[3];
    uint4 lo, hi;
    lo.x = pack2bf(v0.x, v0.y); lo.y = pack2bf(v0.z, v0.w);
    lo.z = pack2bf(v1.x, v1.y); lo.w = pack2bf(v1.z, v1.w);
    hi.x = pack2bf(v2.x, v2.y); hi.y = pack2bf(v2.z, v2.w);
    hi.z = pack2bf(v3.x, v3.y); hi.w = pack2bf(v3.z, v3.w);
    int kp = lane >> 1;
    int key = (pos >> 1) & 3;
    int c0 = (lane & 1) * 2;
    size_t base = (size_t)kp * PROWS + (size_t)s * 32;
    *(uint4*)&apk[base + ((c0 ^ key) * 8)]       = lo;
    *(uint4*)&apk[base + (((c0+1) ^ key) * 8)]   = hi;
}

// ---------------- GEMM1: HH = (X@W1+b1) * silu(X@W2+b2), per expert ----------------
// 256x128 tile, 8 waves (2M x 4N), per-wave 128x32, BOTH matrices.
// 8-phase template: K-tile=64 (2 panels), 4 phases/K-tile = {panel x row-half},
// 16 MFMA/phase, 2 raw barriers/phase, staging 1 unit (2 gloads) per phase,
// counted vmcnt(4)/vmcnt(2) derived per-ledger (never 0 except tail).
__global__ __launch_bounds__(512, 2) void k_gemm1(
    const unsigned short* __restrict__ apk,
    const unsigned short* __restrict__ w1p, const unsigned short* __restrict__ w2p,
    const float* __restrict__ b1, const float* __restrict__ b2,
    const int* __restrict__ counts, const int* __restrict__ offsets,
    unsigned short* __restrict__ hh2) {
    int e = blockIdx.z;
    int n_e = counts[e];
    int m0 = blockIdx.y * 256;
    if (m0 >= n_e) return;
    int base = offsets[e];
    int hp = blockIdx.x;                 // 128-col h-panel
    int n0 = hp * 128;

    __shared__ __align__(16) unsigned short sA[2][2][8192];   // [slot][panel][256*32] = 64KB
    __shared__ __align__(16) unsigned short sW1[2][8192];     // [slot][2 panels * 128*32] = 32KB
    __shared__ __align__(16) unsigned short sW2[2][8192];     // 32KB   -> 128KB total

    int tid = threadIdx.x;
    int wid = tid >> 6, lane = tid & 63;
    int wr = wid >> 2, wc = wid & 3;     // 2M x 4N

    // contiguous staging sources
    const unsigned short* aSrc  = apk + (size_t)(base + m0 + wid*32)*32 + lane*8;      // +kp*PROWS
    const size_t wOff = (size_t)(e*32 + hp) * 32 * 4096;
    const unsigned short* w1Src = w1p + wOff + wid*1024 + lane*8;                      // +kt*8192
    const unsigned short* w2Src = w2p + wOff + wid*1024 + lane*8;

    // fragment LDS offsets (chunk-XOR swizzle; key reduces to (arow>>1)&3)
    int arow = lane & 15, cr = lane >> 4;
    int ccf = cr ^ ((arow >> 1) & 3);
    int aoff[8], woff[2];
    #pragma unroll
    for (int rf = 0; rf < 8; rf++) aoff[rf] = (wr*128 + rf*16 + arow)*32 + ccf*8;
    #pragma unroll
    for (int cf = 0; cf < 2; cf++) woff[cf] = (wc*32 + cf*16 + arow)*32 + ccf*8;

    f32x4 acc1[8][2], acc2[8][2];
    #pragma unroll
    for (int rf = 0; rf < 8; rf++)
        #pragma unroll
        for (int cf = 0; cf < 2; cf++)
            #pragma unroll
            for (int j = 0; j < 4; j++) { acc1[rf][cf][j] = 0.0f; acc2[rf][cf][j] = 0.0f; }

    bf16x8 af[4], w1f[2], w2f[2];

    auto ST_W1 = [&](int ss, int kt) {
        const unsigned short* s_ = w1Src + (size_t)kt*8192;
        unsigned short* d_ = &sW1[ss][0] + wid*1024;
        gload16(s_, d_); gload16(s_ + 512, d_ + 512);
    };
    auto ST_W2 = [&](int ss, int kt) {
        const unsigned short* s_ = w2Src + (size_t)kt*8192;
        unsigned short* d_ = &sW2[ss][0] + wid*1024;
        gload16(s_, d_); gload16(s_ + 512, d_ + 512);
    };
    auto ST_A = [&](int ss, int p, int kp) {
        const unsigned short* s_ = aSrc + (size_t)kp*PROWS;
        unsigned short* d_ = &sA[ss][p][0] + wid*1024;
        gload16(s_, d_); gload16(s_ + 512, d_ + 512);
    };

#define LDA1(SLOT, P, RB) { const unsigned short* lA_ = &sA[SLOT][P][0]; \
    _Pragma("unroll") for (int rf_ = 0; rf_ < 4; rf_++) af[rf_] = *(const bf16x8*)&lA_[aoff[(RB)+rf_]]; }
#define LDW1(SLOT, P) { const unsigned short* l1_ = &sW1[SLOT][(P)*4096]; \
    const unsigned short* l2_ = &sW2[SLOT][(P)*4096]; \
    _Pragma("unroll") for (int cf_ = 0; cf_ < 2; cf_++) { \
        w1f[cf_] = *(const bf16x8*)&l1_[woff[cf_]]; \
        w2f[cf_] = *(const bf16x8*)&l2_[woff[cf_]]; } }
#define MM1P(RB) { __builtin_amdgcn_s_setprio(1); \
    _Pragma("unroll") for (int rf_ = 0; rf_ < 4; rf_++) \
        _Pragma("unroll") for (int cf_ = 0; cf_ < 2; cf_++) { \
            acc1[(RB)+rf_][cf_] = __builtin_amdgcn_mfma_f32_16x16x32_bf16(af[rf_], w1f[cf_], acc1[(RB)+rf_][cf_], 0, 0, 0); \
            acc2[(RB)+rf_][cf_] = __builtin_amdgcn_mfma_f32_16x16x32_bf16(af[rf_], w2f[cf_], acc2[(RB)+rf_][cf_], 0, 0, 0); } \
    __builtin_amdgcn_s_setprio(0); }

    // prologue: stage K-tile 0 (order: W1, W2, A-p0, A-p1); need first 6 -> vmcnt(2)
    ST_W1(0, 0); ST_W2(0, 0); ST_A(0, 0, 0); ST_A(0, 1, 1);
    asm volatile("s_waitcnt vmcnt(2)" ::: "memory");
    fence_bar();

    for (int g = 0; g < NKT1; ++g) {
        int s = g & 1, ss = s ^ 1;
        bool st = (g + 1 < NKT1);
        // ---- phase 1: panel0, rows[0:64); stage W1(g+1)
        LDA1(s, 0, 0); LDW1(s, 0);
        if (st) ST_W1(ss, g + 1);
        fence_bar();
        MM1P(0);
        fence_bar();
        // ---- phase 2: panel0, rows[64:128); stage W2(g+1); vmcnt(4) drains A-p1(g)
        LDA1(s, 0, 4);
        if (st) ST_W2(ss, g + 1);
        fence_bar();
        MM1P(4);
        if (st) { asm volatile("s_waitcnt vmcnt(4)" ::: "memory"); }
        else    { asm volatile("s_waitcnt vmcnt(0)" ::: "memory"); }
        fence_bar();
        // ---- phase 3: panel1, rows[0:64); stage A-p0(g+1)
        LDA1(s, 1, 0); LDW1(s, 1);
        if (st) ST_A(ss, 0, 2*(g+1));
        fence_bar();
        MM1P(0);
        fence_bar();
        // ---- phase 4: panel1, rows[64:128); stage A-p1(g+1); vmcnt(2) drains W1,W2,A-p0(g+1)
        LDA1(s, 1, 4);
        if (st) ST_A(ss, 1, 2*(g+1) + 1);
        fence_bar();
        MM1P(4);
        if (st) { asm volatile("s_waitcnt vmcnt(2)" ::: "memory"); }
        fence_bar();
    }

    // epilogue -> HH2 panel-major [hp2=128][SLOTPAD][32], chunk-XOR key = expert-local row
    int lrow = (lane >> 4) * 4, lcol = lane & 15;
    #pragma unroll
    for (int cf = 0; cf < 2; cf++) {
        int hcol = n0 + wc*32 + cf*16 + lcol;
        float bias1 = b1[e*Hc + hcol], bias2 = b2[e*Hc + hcol];
        int hp2 = hcol >> 5;
        int ch  = (hcol >> 3) & 3;
        int ho  = hcol & 7;
        #pragma unroll
        for (int rf = 0; rf < 8; rf++) {
            int rb2 = m0 + wr*128 + rf*16 + lrow;
            #pragma unroll
            for (int j = 0; j < 4; j++) {
                int r = rb2 + j;
                if (r < n_e) {
                    float h1v = acc1[rf][cf][j] + bias1;
                    float h2v = acc2[rf][cf][j] + bias2;
                    float hhv = h1v * (h2v / (1.0f + expf(-h2v)));   // h1 * silu(h2)
                    int key = (r >> 1) & 3;
                    hh2[(size_t)hp2 * PROWS + (size_t)(base + r)*32 + ((ch ^ key)*8) + ho] = f2bf(hhv);
                }
            }
        }
    }
#undef LDA1
#undef LDW1
#undef MM1P
}

// ---------------- GEMM2: OUT = HH @ Wp^T + bp, per expert ----------------
// 256x128 tile, 8 waves (4M x 2N), per-wave 64x64. K-tile=64, 2 phases/K-tile,
// 3-slot ring (stage K-tile j+2 during group j), vmcnt(6) once per K-tile.
__global__ __launch_bounds__(512, 2) void k_gemm2(
    const unsigned short* __restrict__ hh2,
    const unsigned short* __restrict__ wpp,
    const float* __restrict__ bp,
    const int* __restrict__ counts, const int* __restrict__ offsets,
    float* __restrict__ outb) {
    int e = blockIdx.z;
    int n_e = counts[e];
    int m0 = blockIdx.y * 256;
    if (m0 >= n_e) return;
    int base = offsets[e];
    int dp = blockIdx.x;
    int n0 = dp * 128;

    __shared__ __align__(16) unsigned short sA2[3][2][8192];  // 96KB
    __shared__ __align__(16) unsigned short sB2[3][8192];     // 48KB -> 144KB total

    int tid = threadIdx.x;
    int wid = tid >> 6, lane = tid & 63;
    int wr = wid >> 1, wc = wid & 1;     // 4M x 2N

    const unsigned short* aSrc = hh2 + (size_t)(base + m0 + wid*32)*32 + lane*8;       // +kp*PROWS
    const unsigned short* bSrc = wpp + (size_t)e*Hc*Dc + (size_t)dp*128*4096
                                     + wid*1024 + lane*8;                               // +kt*8192

    int arow = lane & 15, cr = lane >> 4;
    int ccf = cr ^ ((arow >> 1) & 3);
    int aoff[4], boff[4];
    #pragma unroll
    for (int rf = 0; rf < 4; rf++) aoff[rf] = (wr*64 + rf*16 + arow)*32 + ccf*8;
    #pragma unroll
    for (int cf = 0; cf < 4; cf++) boff[cf] = (wc*64 + cf*16 + arow)*32 + ccf*8;

    f32x4 acc[4][4];
    #pragma unroll
    for (int rf = 0; rf < 4; rf++)
        #pragma unroll
        for (int cf = 0; cf < 4; cf++)
            #pragma unroll
            for (int j = 0; j < 4; j++) acc[rf][cf][j] = 0.0f;

    bf16x8 af[4], bf[4];

    auto ST_A2 = [&](int ss, int p, int kp) {
        const unsigned short* s_ = aSrc + (size_t)kp*PROWS;
        unsigned short* d_ = &sA2[ss][p][0] + wid*1024;
        gload16(s_, d_); gload16(s_ + 512, d_ + 512);
    };
    auto ST_B2 = [&](int ss, int kt) {
        const unsigned short* s_ = bSrc + (size_t)kt*8192;
        unsigned short* d_ = &sB2[ss][0] + wid*1024;
        gload16(s_, d_); gload16(s_ + 512, d_ + 512);
    };

#define LDA2(SLOT, P) { const unsigned short* lA_ = &sA2[SLOT][P][0]; \
    _Pragma("unroll") for (int rf_ = 0; rf_ < 4; rf_++) af[rf_] = *(const bf16x8*)&lA_[aoff[rf_]]; }
#define LDB2(SLOT, P) { const unsigned short* lB_ = &sB2[SLOT][(P)*4096]; \
    _Pragma("unroll") for (int cf_ = 0; cf_ < 4; cf_++) bf[cf_] = *(const bf16x8*)&lB_[boff[cf_]]; }
#define MM2P() { __builtin_amdgcn_s_setprio(1); \
    _Pragma("unroll") for (int rf_ = 0; rf_ < 4; rf_++) \
        _Pragma("unroll") for (int cf_ = 0; cf_ < 4; cf_++) \
            acc[rf_][cf_] = __builtin_amdgcn_mfma_f32_16x16x32_bf16(af[rf_], bf[cf_], acc[rf_][cf_], 0, 0, 0); \
    __builtin_amdgcn_s_setprio(0); }

    // prologue: K-tile 0 -> slot0, K-tile 1 -> slot1 (A-p0, A-p1, B each); vmcnt(6)
    ST_A2(0, 0, 0); ST_A2(0, 1, 1); ST_B2(0, 0);
    ST_A2(1, 0, 2); ST_A2(1, 1, 3); ST_B2(1, 1);
    asm volatile("s_waitcnt vmcnt(6)" ::: "memory");
    fence_bar();

    for (int j = 0; j < NKT2; ++j) {
        int s = j % 3, ss = (j + 2) % 3;
        bool st = (j + 2 < NKT2);
        // ---- phase 1: panel0; stage A-p0,A-p1(j+2)
        LDA2(s, 0); LDB2(s, 0);
        if (st) { ST_A2(ss, 0, 2*(j+2)); ST_A2(ss, 1, 2*(j+2) + 1); }
        fence_bar();
        MM2P();
        fence_bar();
        // ---- phase 2: panel1; stage B(j+2); vmcnt(6) drains K-tile j+1's 6 loads
        LDA2(s, 1); LDB2(s, 1);
        if (st) ST_B2(ss, j + 2);
        fence_bar();
        MM2P();
        if (st)                   { asm volatile("s_waitcnt vmcnt(6)" ::: "memory"); }
        else if (j + 1 < NKT2)    { asm volatile("s_waitcnt vmcnt(0)" ::: "memory"); }
        fence_bar();
    }

    int lrow = (lane >> 4) * 4, lcol = lane & 15;
    #pragma unroll
    for (int cf = 0; cf < 4; cf++) {
        int dcol = n0 + wc*64 + cf*16 + lcol;
        float bias = bp[e*Dc + dcol];
        #pragma unroll
        for (int rf = 0; rf < 4; rf++) {
            int rb2 = m0 + wr*64 + rf*16 + lrow;
            #pragma unroll
            for (int j = 0; j < 4; j++) {
                int r = rb2 + j;
                if (r < n_e)
                    outb[(size_t)(base + r)*Dc + dcol] = acc[rf][cf][j] + bias;
            }
        }
    }
#undef LDA2
#undef LDB2
#undef MM2P
}

// ---------------- combine: final[t] = w0*OUT[s0] + w1*OUT[s1] ----------------
__global__ void k_combine(const float* __restrict__ outb, const int* __restrict__ slot_of,
                          const float* __restrict__ tok_w, float* __restrict__ final_out) {
    int gid = blockIdx.x * 256 + threadIdx.x;   // Tc*Dc/4 threads
    int t = gid >> 8;
    int c = (gid & 255) * 4;
    int s0 = slot_of[t*2], s1 = slot_of[t*2 + 1];
    float w0 = tok_w[t*2], w1 = tok_w[t*2 + 1];
    float4 o0 = *(const float4*)&outb[(size_t)s0*Dc + c];
    float4 o1 = *(const float4*)&outb[(size_t)s1*Dc + c];
    float4 r;
    r.x = w0*o0.x + w1*o1.x;
    r.y = w0*o0.y + w1*o1.y;
    r.z = w0*o0.z + w1*o1.z;
    r.w = w0*o0.w + w1*o1.w;
    *(float4*)&final_out[(size_t)t*Dc + c] = r;
}

extern "C" void kernel_launch(void* const* d_in, const int* in_sizes, int n_in,
                              void* d_out, int out_size, void* d_ws, size_t ws_size,
                              hipStream_t stream) {
    (void)in_sizes; (void)n_in; (void)out_size; (void)ws_size;
    const float* x     = (const float*)d_in[0];
    const float* noise = (const float*)d_in[1];
    const float* Wg    = (const float*)d_in[2];
    const float* nw    = (const float*)d_in[3];
    const float* W1    = (const float*)d_in[4];
    const float* b1    = (const float*)d_in[5];
    const float* W2    = (const float*)d_in[6];
    const float* b2    = (const float*)d_in[7];
    const float* Wp    = (const float*)d_in[8];
    const float* bp    = (const float*)d_in[9];

    char* ws = (char*)d_ws;
    size_t off = 0;
    unsigned short* W1P = (unsigned short*)(ws + off); off += (size_t)Ec*Dc*Hc*2;      // 64 MB
    unsigned short* W2P = (unsigned short*)(ws + off); off += (size_t)Ec*Dc*Hc*2;      // 64 MB
    unsigned short* WPP = (unsigned short*)(ws + off); off += (size_t)Ec*Hc*Dc*2;      // 64 MB
    unsigned short* APK = (unsigned short*)(ws + off); off += (size_t)32*PROWS*2;      // 16.5 MB
    unsigned short* HH2 = (unsigned short*)(ws + off); off += (size_t)128*PROWS*2;     // 66 MB
    float*          OUTB= (float*)(ws + off);          off += (size_t)NSLOT*Dc*4;      // 32 MB
    int*   counts    = (int*)(ws + off);
    int*   fill      = (int*)(ws + off + 32);
    int*   offsets   = (int*)(ws + off + 64);
    int*   tok_top   = (int*)(ws + off + 128);
    float* tok_w     = (float*)(ws + off + 128 + (size_t)Tc*2*4);
    int*   slot_token= (int*)(ws + off + 128 + (size_t)Tc*2*8);
    int*   slot_of   = (int*)(ws + off + 128 + (size_t)Tc*2*8 + (size_t)NSLOT*4);
    int*   slot_pos  = (int*)(ws + off + 128 + (size_t)Tc*2*8 + (size_t)NSLOT*8);

    float* final_out = (float*)d_out;
    float* idx_out   = (float*)d_out + FINAL_N;

    hipMemsetAsync(counts, 0, 64, stream);   // counts + fill

    // W1 + W2 panel transposes in one launch (z = 16: [0,8) -> W1, [8,16) -> W2)
    k_transpose_panel<<<dim3(Hc/64, Dc/64, 2*Ec), 256, 0, stream>>>(W1, W2, W1P, W2P, Dc, Hc, Ec);
    k_transpose_panel<<<dim3(Dc/64, Hc/64, Ec), 256, 0, stream>>>(Wp, Wp, WPP, WPP, Hc, Dc, Ec);

    k_gate<<<Tc, 64, 0, stream>>>(x, noise, Wg, nw, idx_out, counts, tok_top, tok_w);
    k_scan<<<1, 64, 0, stream>>>(counts, offsets);
    k_fill<<<Tc/256, 256, 0, stream>>>(tok_top, offsets, fill, slot_token, slot_of, slot_pos);
    k_packA<<<NSLOT/4, 256, 0, stream>>>(x, slot_token, slot_pos, APK);

    k_gemm1<<<dim3(Hc/128, Tc/256, Ec), 512, 0, stream>>>(APK, W1P, W2P, b1, b2,
                                                          counts, offsets, HH2);
    k_gemm2<<<dim3(Dc/128, Tc/256, Ec), 512, 0, stream>>>(HH2, WPP, bp, counts, offsets, OUTB);
    k_combine<<<(Tc*Dc/4)/256, 256, 0, stream>>>(OUTB, slot_of, tok_w, final_out);
}

// Round 5
// 659.979 us; speedup vs baseline: 1.0780x; 1.0780x over previous
//
#include <hip/hip_runtime.h>
#include <math.h>

// MoE: B=2 S=2048 D=1024 E=8 H=4096 K=2
#define Bc 2
#define Sc 2048
#define Dc 1024
#define Ec 8
#define Hc 4096
#define Tc (Bc*Sc)          // 4096 tokens
#define NSLOT (Tc*2)        // 8192 token-expert slots (top-2 always)
#define SLOTPAD 8448        // NSLOT + 256 slack rows (padded tile over-read)
#define FINAL_N ((size_t)Tc*Dc)
#define PROWS ((size_t)SLOTPAD*32)   // ushorts per 32-wide K-panel of A/HH

typedef float f32x4 __attribute__((ext_vector_type(4)));
typedef __bf16 bf16x8 __attribute__((ext_vector_type(8)));

__device__ __forceinline__ unsigned short f2bf(float f) {
    union { float f; unsigned int u; } v; v.f = f;
    return (unsigned short)((v.u + 0x7fffu + ((v.u >> 16) & 1u)) >> 16);
}
__device__ __forceinline__ unsigned int pack2bf(float a, float b) {
    return (unsigned int)f2bf(a) | ((unsigned int)f2bf(b) << 16);
}

// async global->LDS, 16B per lane; contiguous 1KB per instruction (panel-major sources)
__device__ __forceinline__ void gload16(const unsigned short* g, unsigned short* l) {
    __builtin_amdgcn_global_load_lds(
        (const __attribute__((address_space(1))) unsigned int*)g,
        (__attribute__((address_space(3))) unsigned int*)l,
        16, 0, 0);
}

// ------- [R][C] fp32 -> panel-major bf16 [C/128][R/32][128][32], chunk-XOR pre-swizzled -------
__global__ void k_transpose_panel(const float* __restrict__ inA, const float* __restrict__ inB,
                                  unsigned short* __restrict__ outA, unsigned short* __restrict__ outB,
                                  int R, int C, int nz_per_mat) {
    __shared__ float tile[64][65];
    int z = blockIdx.z;
    const float* in; unsigned short* out;
    if (z < nz_per_mat) { in = inA; out = outA; }
    else { in = inB; out = outB; z -= nz_per_mat; }
    size_t zbase = (size_t)z * (size_t)R * C;
    int R32 = R >> 5;
    int cb = blockIdx.x * 64, rb = blockIdx.y * 64;
    int t = threadIdx.x;             // 256
    int q = t & 15, g = t >> 4;
    #pragma unroll
    for (int j = 0; j < 4; j++) {
        int row = g + 16*j;
        float4 v = *(const float4*)&in[zbase + (size_t)(rb+row)*C + cb + q*4];
        tile[row][q*4+0] = v.x; tile[row][q*4+1] = v.y;
        tile[row][q*4+2] = v.z; tile[row][q*4+3] = v.w;
    }
    __syncthreads();
    #pragma unroll
    for (int j = 0; j < 4; j++) {
        int co = g + 16*j;
        int c = cb + co;
        int r0 = rb + q*4;
        ushort4 o;
        o.x = f2bf(tile[q*4+0][co]); o.y = f2bf(tile[q*4+1][co]);
        o.z = f2bf(tile[q*4+2][co]); o.w = f2bf(tile[q*4+3][co]);
        int cr = c & 127;
        int ch = ((r0 >> 3) & 3) ^ ((cr >> 1) & 3);
        size_t off = zbase + (((size_t)(c >> 7) * R32 + (r0 >> 5)) * 4096)
                   + (size_t)cr * 32 + ch * 8 + (r0 & 7);
        *(ushort4*)&out[off] = o;
    }
}

// ---------------- gating: one wave per token ----------------
__global__ void k_gate(const float* __restrict__ x, const float* __restrict__ noise,
                       const float* __restrict__ Wg, const float* __restrict__ nw,
                       float* __restrict__ out_idx, int* __restrict__ counts,
                       int* __restrict__ tok_top, float* __restrict__ tok_w) {
    int t = blockIdx.x;
    int lane = threadIdx.x;                     // 64
    const float* xr = x + (size_t)t * Dc;
    double acc[Ec];
    #pragma unroll
    for (int e = 0; e < Ec; e++) acc[e] = 0.0;
    for (int i = 0; i < Dc/64; i++) {
        int d = lane + i*64;
        double xv = (double)xr[d];
        #pragma unroll
        for (int e = 0; e < Ec; e++) acc[e] += xv * (double)Wg[e*Dc + d];
    }
    #pragma unroll
    for (int e = 0; e < Ec; e++)
        for (int off = 32; off > 0; off >>= 1)
            acc[e] += __shfl_down(acc[e], off);
    if (lane == 0) {
        double noisy[Ec];
        #pragma unroll
        for (int e = 0; e < Ec; e++)
            noisy[e] = acc[e] + (double)noise[t*Ec + e] * (double)nw[e];
        int i0 = 0;
        for (int e = 1; e < Ec; e++) if (noisy[e] > noisy[i0]) i0 = e;   // ties -> lowest idx
        int i1 = -1;
        for (int e = 0; e < Ec; e++) {
            if (e == i0) continue;
            if (i1 < 0 || noisy[e] > noisy[i1]) i1 = e;
        }
        double ee = exp(noisy[i1] - noisy[i0]);   // v1 <= v0, stable
        float w0 = (float)(1.0 / (1.0 + ee));
        float w1 = (float)(ee / (1.0 + ee));
        out_idx[t*2 + 0] = (float)i0;
        out_idx[t*2 + 1] = (float)i1;
        tok_top[t*2] = i0; tok_top[t*2+1] = i1;
        tok_w[t*2] = w0;   tok_w[t*2+1] = w1;
        atomicAdd(&counts[i0], 1);
        atomicAdd(&counts[i1], 1);
    }
}

__global__ void k_scan(const int* __restrict__ counts, int* __restrict__ offsets) {
    if (threadIdx.x == 0) {
        int s = 0;
        for (int e = 0; e < Ec; e++) { offsets[e] = s; s += counts[e]; }
        offsets[Ec] = s;
    }
}

__global__ void k_fill(const int* __restrict__ tok_top, const int* __restrict__ offsets,
                       int* __restrict__ fill, int* __restrict__ slot_token,
                       int* __restrict__ slot_of, int* __restrict__ slot_pos) {
    int t = blockIdx.x * 256 + threadIdx.x;
    if (t >= Tc) return;
    #pragma unroll
    for (int j = 0; j < 2; j++) {
        int e = tok_top[t*2 + j];
        int pos = atomicAdd(&fill[e], 1);
        int slot = offsets[e] + pos;
        slot_token[slot] = t;
        slot_of[t*2 + j] = slot;
        slot_pos[slot] = pos;                 // expert-local row (swizzle key source)
    }
}

// ---- pack A: gather + cvt into K-panel-major APK[kp=32][SLOTPAD][32], pre-swizzled ----
__global__ void k_packA(const float* __restrict__ x, const int* __restrict__ slot_token,
                        const int* __restrict__ slot_pos, unsigned short* __restrict__ apk) {
    int s = blockIdx.x * 4 + (threadIdx.x >> 6);
    int lane = threadIdx.x & 63;
    int token = slot_token[s];
    int pos = slot_pos[s];
    const float4* px = (const float4*)(x + (size_t)token * Dc) + lane*4;
    float4 v0 = px[0], v1 = px[1], v2 = px[2], v3 = px[3];
    uint4 lo, hi;
    lo.x = pack2bf(v0.x, v0.y); lo.y = pack2bf(v0.z, v0.w);
    lo.z = pack2bf(v1.x, v1.y); lo.w = pack2bf(v1.z, v1.w);
    hi.x = pack2bf(v2.x, v2.y); hi.y = pack2bf(v2.z, v2.w);
    hi.z = pack2bf(v3.x, v3.y); hi.w = pack2bf(v3.z, v3.w);
    int kp = lane >> 1;
    int key = (pos >> 1) & 3;
    int c0 = (lane & 1) * 2;
    size_t base = (size_t)kp * PROWS + (size_t)s * 32;
    *(uint4*)&apk[base + ((c0 ^ key) * 8)]       = lo;
    *(uint4*)&apk[base + (((c0+1) ^ key) * 8)]   = hi;
}

// ---------------- GEMM1: HH = (X@W1+b1) * silu(X@W2+b2), per expert ----------------
// m97-faithful cell: 128x128 tile (128 slots x 64 hcols x {W1,W2}), 4 waves, single acc/wave,
// 16KB single-buffered LDS, 2 __syncthreads/iter, 4 blocks/CU (launch_bounds(256,4)).
// B-tile rows 0-63 = W1[n0..n0+64), rows 64-127 = W2 same cols; wc selects matrix.
// SwiGLU product formed in-block via 32KB LDS union in the epilogue (f32 throughout).
__global__ __launch_bounds__(256, 4) void k_gemm1(
    const unsigned short* __restrict__ apk,
    const unsigned short* __restrict__ w1p, const unsigned short* __restrict__ w2p,
    const float* __restrict__ b1, const float* __restrict__ b2,
    const int* __restrict__ counts, const int* __restrict__ offsets,
    unsigned short* __restrict__ hh2) {
    int e = blockIdx.z;
    int n_e = counts[e];
    int m0 = blockIdx.y * 128;
    if (m0 >= n_e) return;
    int base = offsets[e];
    int bx = blockIdx.x;                 // 64 x-blocks of 64 h-cols
    int n0 = bx * 64;
    int hp = bx >> 1, ro = (bx & 1) * 64;   // 128-panel + row offset inside it

    __shared__ __align__(16) unsigned char smem[32768];
    unsigned short* sA = (unsigned short*)smem;            // [128][32] slots
    unsigned short* sB = (unsigned short*)(smem + 16384);  // [128][32] W1|W2
    float* sS = (float*)smem;                              // [128][64] epilogue silu (aliases)

    int tid = threadIdx.x;
    int wid = tid >> 6, lane = tid & 63;
    int wr = wid >> 1, wc = wid & 1;

    // contiguous staging sources
    const unsigned short* aSrc = apk + (size_t)(base + m0 + wid*32)*32 + lane*8;   // + kk*PROWS
    const unsigned short* wmat = (wid < 2) ? w1p : w2p;
    const unsigned short* bSrc = wmat + ((size_t)(e*32 + hp) * 32) * 4096
                               + (size_t)(ro + (wid & 1)*32)*32 + lane*8;          // + kk*4096

    int arow = lane & 15, cr = lane >> 4;
    int ccf = cr ^ ((arow >> 1) & 3);
    int aoff[4], boff[4];
    #pragma unroll
    for (int m = 0; m < 4; m++) aoff[m] = (wr*64 + m*16 + arow)*32 + ccf*8;
    #pragma unroll
    for (int n = 0; n < 4; n++) boff[n] = (wc*64 + n*16 + arow)*32 + ccf*8;

    f32x4 acc[4][4];
    #pragma unroll
    for (int m = 0; m < 4; m++)
        #pragma unroll
        for (int n = 0; n < 4; n++)
            #pragma unroll
            for (int j = 0; j < 4; j++) acc[m][n][j] = 0.0f;

    unsigned short* dA = sA + wid*1024;
    unsigned short* dB = sB + wid*1024;

    const int NK = Dc / 32;   // 32
    for (int kk = 0; kk < NK; ++kk) {
        const unsigned short* a = aSrc + (size_t)kk*PROWS;
        const unsigned short* b = bSrc + (size_t)kk*4096;
        gload16(a,       dA); gload16(a + 512, dA + 512);
        gload16(b,       dB); gload16(b + 512, dB + 512);
        __syncthreads();
        bf16x8 af[4], bf[4];
        #pragma unroll
        for (int m = 0; m < 4; m++) af[m] = *(const bf16x8*)&sA[aoff[m]];
        #pragma unroll
        for (int n = 0; n < 4; n++) bf[n] = *(const bf16x8*)&sB[boff[n]];
        #pragma unroll
        for (int m = 0; m < 4; m++)
            #pragma unroll
            for (int n = 0; n < 4; n++)
                acc[m][n] = __builtin_amdgcn_mfma_f32_16x16x32_bf16(af[m], bf[n], acc[m][n], 0, 0, 0);
        __syncthreads();
    }

    // epilogue: wc=1 waves publish silu(h2) to LDS (f32); wc=0 multiply and store HH2
    int lrow = (lane >> 4) * 4, lcol = lane & 15;
    if (wc == 1) {
        #pragma unroll
        for (int n = 0; n < 4; n++) {
            float b2v = b2[e*Hc + n0 + n*16 + lcol];
            #pragma unroll
            for (int m = 0; m < 4; m++) {
                int rb = wr*64 + m*16 + lrow;
                #pragma unroll
                for (int j = 0; j < 4; j++) {
                    float h2 = acc[m][n][j] + b2v;
                    sS[(rb + j)*64 + n*16 + lcol] = h2 / (1.0f + expf(-h2));
                }
            }
        }
    }
    __syncthreads();
    if (wc == 0) {
        #pragma unroll
        for (int n = 0; n < 4; n++) {
            int hcol = n0 + n*16 + lcol;
            float b1v = b1[e*Hc + hcol];
            int hp2 = hcol >> 5;
            int ch  = (hcol >> 3) & 3;
            int ho  = hcol & 7;
            #pragma unroll
            for (int m = 0; m < 4; m++) {
                int rb = wr*64 + m*16 + lrow;
                #pragma unroll
                for (int j = 0; j < 4; j++) {
                    int r = m0 + rb + j;
                    if (r < n_e) {
                        float v = (acc[m][n][j] + b1v) * sS[(rb + j)*64 + n*16 + lcol];
                        int key = (r >> 1) & 3;
                        hh2[(size_t)hp2 * PROWS + (size_t)(base + r)*32 + ((ch ^ key)*8) + ho] = f2bf(v);
                    }
                }
            }
        }
    }
}

// ---------------- GEMM2: OUT = HH @ Wp^T + bp, per expert ----------------
// m97-faithful: 128x128 tile, 4 waves, 64x64/wave, 16KB single-buffered LDS,
// 2 __syncthreads/iter, 4 blocks/CU.
__global__ __launch_bounds__(256, 4) void k_gemm2(
    const unsigned short* __restrict__ hh2,
    const unsigned short* __restrict__ wpp,
    const float* __restrict__ bp,
    const int* __restrict__ counts, const int* __restrict__ offsets,
    float* __restrict__ outb) {
    int e = blockIdx.z;
    int n_e = counts[e];
    int m0 = blockIdx.y * 128;
    if (m0 >= n_e) return;
    int base = offsets[e];
    int dp = blockIdx.x;
    int n0 = dp * 128;

    __shared__ __align__(16) unsigned short sA[128*32];   // 8KB
    __shared__ __align__(16) unsigned short sB[128*32];   // 8KB

    int tid = threadIdx.x;
    int wid = tid >> 6, lane = tid & 63;
    int wr = wid >> 1, wc = wid & 1;

    const unsigned short* aSrc = hh2 + (size_t)(base + m0 + wid*32)*32 + lane*8;     // + kk*PROWS
    const unsigned short* bSrc = wpp + ((size_t)(e*8 + dp) * 128) * 4096
                               + wid*1024 + lane*8;                                   // + kk*4096

    int arow = lane & 15, cr = lane >> 4;
    int ccf = cr ^ ((arow >> 1) & 3);
    int aoff[4], boff[4];
    #pragma unroll
    for (int m = 0; m < 4; m++) aoff[m] = (wr*64 + m*16 + arow)*32 + ccf*8;
    #pragma unroll
    for (int n = 0; n < 4; n++) boff[n] = (wc*64 + n*16 + arow)*32 + ccf*8;

    f32x4 acc[4][4];
    #pragma unroll
    for (int m = 0; m < 4; m++)
        #pragma unroll
        for (int n = 0; n < 4; n++)
            #pragma unroll
            for (int j = 0; j < 4; j++) acc[m][n][j] = 0.0f;

    unsigned short* dA = sA + wid*1024;
    unsigned short* dB = sB + wid*1024;

    const int NK = Hc / 32;   // 128
    for (int kk = 0; kk < NK; ++kk) {
        const unsigned short* a = aSrc + (size_t)kk*PROWS;
        const unsigned short* b = bSrc + (size_t)kk*4096;
        gload16(a,       dA); gload16(a + 512, dA + 512);
        gload16(b,       dB); gload16(b + 512, dB + 512);
        __syncthreads();
        bf16x8 af[4], bf[4];
        #pragma unroll
        for (int m = 0; m < 4; m++) af[m] = *(const bf16x8*)&sA[aoff[m]];
        #pragma unroll
        for (int n = 0; n < 4; n++) bf[n] = *(const bf16x8*)&sB[boff[n]];
        #pragma unroll
        for (int m = 0; m < 4; m++)
            #pragma unroll
            for (int n = 0; n < 4; n++)
                acc[m][n] = __builtin_amdgcn_mfma_f32_16x16x32_bf16(af[m], bf[n], acc[m][n], 0, 0, 0);
        __syncthreads();
    }

    int lrow = (lane >> 4) * 4, lcol = lane & 15;
    #pragma unroll
    for (int n = 0; n < 4; n++) {
        int dcol = n0 + wc*64 + n*16 + lcol;
        float bias = bp[e*Dc + dcol];
        #pragma unroll
        for (int m = 0; m < 4; m++) {
            int rb2 = m0 + wr*64 + m*16 + lrow;
            #pragma unroll
            for (int j = 0; j < 4; j++) {
                int r = rb2 + j;
                if (r < n_e)
                    outb[(size_t)(base + r)*Dc + dcol] = acc[m][n][j] + bias;
            }
        }
    }
}

// ---------------- combine: final[t] = w0*OUT[s0] + w1*OUT[s1] ----------------
__global__ void k_combine(const float* __restrict__ outb, const int* __restrict__ slot_of,
                          const float* __restrict__ tok_w, float* __restrict__ final_out) {
    int gid = blockIdx.x * 256 + threadIdx.x;   // Tc*Dc/4 threads
    int t = gid >> 8;
    int c = (gid & 255) * 4;
    int s0 = slot_of[t*2], s1 = slot_of[t*2 + 1];
    float w0 = tok_w[t*2], w1 = tok_w[t*2 + 1];
    float4 o0 = *(const float4*)&outb[(size_t)s0*Dc + c];
    float4 o1 = *(const float4*)&outb[(size_t)s1*Dc + c];
    float4 r;
    r.x = w0*o0.x + w1*o1.x;
    r.y = w0*o0.y + w1*o1.y;
    r.z = w0*o0.z + w1*o1.z;
    r.w = w0*o0.w + w1*o1.w;
    *(float4*)&final_out[(size_t)t*Dc + c] = r;
}

extern "C" void kernel_launch(void* const* d_in, const int* in_sizes, int n_in,
                              void* d_out, int out_size, void* d_ws, size_t ws_size,
                              hipStream_t stream) {
    (void)in_sizes; (void)n_in; (void)out_size; (void)ws_size;
    const float* x     = (const float*)d_in[0];
    const float* noise = (const float*)d_in[1];
    const float* Wg    = (const float*)d_in[2];
    const float* nw    = (const float*)d_in[3];
    const float* W1    = (const float*)d_in[4];
    const float* b1    = (const float*)d_in[5];
    const float* W2    = (const float*)d_in[6];
    const float* b2    = (const float*)d_in[7];
    const float* Wp    = (const float*)d_in[8];
    const float* bp    = (const float*)d_in[9];

    char* ws = (char*)d_ws;
    size_t off = 0;
    unsigned short* W1P = (unsigned short*)(ws + off); off += (size_t)Ec*Dc*Hc*2;      // 64 MB
    unsigned short* W2P = (unsigned short*)(ws + off); off += (size_t)Ec*Dc*Hc*2;      // 64 MB
    unsigned short* WPP = (unsigned short*)(ws + off); off += (size_t)Ec*Hc*Dc*2;      // 64 MB
    unsigned short* APK = (unsigned short*)(ws + off); off += (size_t)32*PROWS*2;      // 16.5 MB
    unsigned short* HH2 = (unsigned short*)(ws + off); off += (size_t)128*PROWS*2;     // 66 MB
    float*          OUTB= (float*)(ws + off);          off += (size_t)NSLOT*Dc*4;      // 32 MB
    int*   counts    = (int*)(ws + off);
    int*   fill      = (int*)(ws + off + 32);
    int*   offsets   = (int*)(ws + off + 64);
    int*   tok_top   = (int*)(ws + off + 128);
    float* tok_w     = (float*)(ws + off + 128 + (size_t)Tc*2*4);
    int*   slot_token= (int*)(ws + off + 128 + (size_t)Tc*2*8);
    int*   slot_of   = (int*)(ws + off + 128 + (size_t)Tc*2*8 + (size_t)NSLOT*4);
    int*   slot_pos  = (int*)(ws + off + 128 + (size_t)Tc*2*8 + (size_t)NSLOT*8);

    float* final_out = (float*)d_out;
    float* idx_out   = (float*)d_out + FINAL_N;

    hipMemsetAsync(counts, 0, 64, stream);   // counts + fill

    // W1 + W2 panel transposes in one launch (z = 16: [0,8) -> W1, [8,16) -> W2)
    k_transpose_panel<<<dim3(Hc/64, Dc/64, 2*Ec), 256, 0, stream>>>(W1, W2, W1P, W2P, Dc, Hc, Ec);
    k_transpose_panel<<<dim3(Dc/64, Hc/64, Ec), 256, 0, stream>>>(Wp, Wp, WPP, WPP, Hc, Dc, Ec);

    k_gate<<<Tc, 64, 0, stream>>>(x, noise, Wg, nw, idx_out, counts, tok_top, tok_w);
    k_scan<<<1, 64, 0, stream>>>(counts, offsets);
    k_fill<<<Tc/256, 256, 0, stream>>>(tok_top, offsets, fill, slot_token, slot_of, slot_pos);
    k_packA<<<NSLOT/4, 256, 0, stream>>>(x, slot_token, slot_pos, APK);

    k_gemm1<<<dim3(Hc/64, Tc/128, Ec), 256, 0, stream>>>(APK, W1P, W2P, b1, b2,
                                                         counts, offsets, HH2);
    k_gemm2<<<dim3(Dc/128, Tc/128, Ec), 256, 0, stream>>>(HH2, WPP, bp, counts, offsets, OUTB);
    k_combine<<<(Tc*Dc/4)/256, 256, 0, stream>>>(OUTB, slot_of, tok_w, final_out);
}

// Round 7
// 645.947 us; speedup vs baseline: 1.1014x; 1.0217x over previous
//
#include <hip/hip_runtime.h>
#include <math.h>

// MoE: B=2 S=2048 D=1024 E=8 H=4096 K=2
#define Bc 2
#define Sc 2048
#define Dc 1024
#define Ec 8
#define Hc 4096
#define Tc (Bc*Sc)          // 4096 tokens
#define NSLOT (Tc*2)        // 8192 token-expert slots (top-2 always)
#define SLOTPAD 8448        // NSLOT + 256 slack rows (padded tile over-read)
#define FINAL_N ((size_t)Tc*Dc)
#define PROWS ((size_t)SLOTPAD*32)   // ushorts per 32-wide K-panel of A/HH

typedef float f32x4 __attribute__((ext_vector_type(4)));
typedef __bf16 bf16x8 __attribute__((ext_vector_type(8)));

__device__ __forceinline__ unsigned short f2bf(float f) {
    union { float f; unsigned int u; } v; v.f = f;
    return (unsigned short)((v.u + 0x7fffu + ((v.u >> 16) & 1u)) >> 16);
}
__device__ __forceinline__ unsigned int pack2bf(float a, float b) {
    return (unsigned int)f2bf(a) | ((unsigned int)f2bf(b) << 16);
}

// async global->LDS, 16B per lane; contiguous 1KB per instruction (panel-major sources)
__device__ __forceinline__ void gload16(const unsigned short* g, unsigned short* l) {
    __builtin_amdgcn_global_load_lds(
        (const __attribute__((address_space(1))) unsigned int*)g,
        (__attribute__((address_space(3))) unsigned int*)l,
        16, 0, 0);
}

// raw barrier with compiler fences (NO vmcnt(0) drain, unlike __syncthreads)
__device__ __forceinline__ void fence_bar() {
    __builtin_amdgcn_sched_barrier(0);
    asm volatile("s_barrier" ::: "memory");
    __builtin_amdgcn_sched_barrier(0);
}

// ------- [R][C] fp32 -> panel-major bf16 [C/128][R/32][128][32], chunk-XOR pre-swizzled -------
__global__ void k_transpose_panel(const float* __restrict__ inA, const float* __restrict__ inB,
                                  unsigned short* __restrict__ outA, unsigned short* __restrict__ outB,
                                  int R, int C, int nz_per_mat) {
    __shared__ float tile[64][65];
    int z = blockIdx.z;
    const float* in; unsigned short* out;
    if (z < nz_per_mat) { in = inA; out = outA; }
    else { in = inB; out = outB; z -= nz_per_mat; }
    size_t zbase = (size_t)z * (size_t)R * C;
    int R32 = R >> 5;
    int cb = blockIdx.x * 64, rb = blockIdx.y * 64;
    int t = threadIdx.x;             // 256
    int q = t & 15, g = t >> 4;
    #pragma unroll
    for (int j = 0; j < 4; j++) {
        int row = g + 16*j;
        float4 v = *(const float4*)&in[zbase + (size_t)(rb+row)*C + cb + q*4];
        tile[row][q*4+0] = v.x; tile[row][q*4+1] = v.y;
        tile[row][q*4+2] = v.z; tile[row][q*4+3] = v.w;
    }
    __syncthreads();
    #pragma unroll
    for (int j = 0; j < 4; j++) {
        int co = g + 16*j;
        int c = cb + co;
        int r0 = rb + q*4;
        ushort4 o;
        o.x = f2bf(tile[q*4+0][co]); o.y = f2bf(tile[q*4+1][co]);
        o.z = f2bf(tile[q*4+2][co]); o.w = f2bf(tile[q*4+3][co]);
        int cr = c & 127;
        int ch = ((r0 >> 3) & 3) ^ ((cr >> 1) & 3);
        size_t off = zbase + (((size_t)(c >> 7) * R32 + (r0 >> 5)) * 4096)
                   + (size_t)cr * 32 + ch * 8 + (r0 & 7);
        *(ushort4*)&out[off] = o;
    }
}

// ---------------- gating: one wave per token ----------------
__global__ void k_gate(const float* __restrict__ x, const float* __restrict__ noise,
                       const float* __restrict__ Wg, const float* __restrict__ nw,
                       float* __restrict__ out_idx, int* __restrict__ counts,
                       int* __restrict__ tok_top, float* __restrict__ tok_w) {
    int t = blockIdx.x;
    int lane = threadIdx.x;                     // 64
    const float* xr = x + (size_t)t * Dc;
    double acc[Ec];
    #pragma unroll
    for (int e = 0; e < Ec; e++) acc[e] = 0.0;
    for (int i = 0; i < Dc/64; i++) {
        int d = lane + i*64;
        double xv = (double)xr[d];
        #pragma unroll
        for (int e = 0; e < Ec; e++) acc[e] += xv * (double)Wg[e*Dc + d];
    }
    #pragma unroll
    for (int e = 0; e < Ec; e++)
        for (int off = 32; off > 0; off >>= 1)
            acc[e] += __shfl_down(acc[e], off);
    if (lane == 0) {
        double noisy[Ec];
        #pragma unroll
        for (int e = 0; e < Ec; e++)
            noisy[e] = acc[e] + (double)noise[t*Ec + e] * (double)nw[e];
        int i0 = 0;
        for (int e = 1; e < Ec; e++) if (noisy[e] > noisy[i0]) i0 = e;   // ties -> lowest idx
        int i1 = -1;
        for (int e = 0; e < Ec; e++) {
            if (e == i0) continue;
            if (i1 < 0 || noisy[e] > noisy[i1]) i1 = e;
        }
        double ee = exp(noisy[i1] - noisy[i0]);   // v1 <= v0, stable
        float w0 = (float)(1.0 / (1.0 + ee));
        float w1 = (float)(ee / (1.0 + ee));
        out_idx[t*2 + 0] = (float)i0;
        out_idx[t*2 + 1] = (float)i1;
        tok_top[t*2] = i0; tok_top[t*2+1] = i1;
        tok_w[t*2] = w0;   tok_w[t*2+1] = w1;
        atomicAdd(&counts[i0], 1);
        atomicAdd(&counts[i1], 1);
    }
}

__global__ void k_scan(const int* __restrict__ counts, int* __restrict__ offsets) {
    if (threadIdx.x == 0) {
        int s = 0;
        for (int e = 0; e < Ec; e++) { offsets[e] = s; s += counts[e]; }
        offsets[Ec] = s;
    }
}

__global__ void k_fill(const int* __restrict__ tok_top, const int* __restrict__ offsets,
                       int* __restrict__ fill, int* __restrict__ slot_token,
                       int* __restrict__ slot_of, int* __restrict__ slot_pos) {
    int t = blockIdx.x * 256 + threadIdx.x;
    if (t >= Tc) return;
    #pragma unroll
    for (int j = 0; j < 2; j++) {
        int e = tok_top[t*2 + j];
        int pos = atomicAdd(&fill[e], 1);
        int slot = offsets[e] + pos;
        slot_token[slot] = t;
        slot_of[t*2 + j] = slot;
        slot_pos[slot] = pos;                 // expert-local row (swizzle key source)
    }
}

// ---- pack A: gather + cvt into K-panel-major APK[kp=32][SLOTPAD][32], pre-swizzled ----
__global__ void k_packA(const float* __restrict__ x, const int* __restrict__ slot_token,
                        const int* __restrict__ slot_pos, unsigned short* __restrict__ apk) {
    int s = blockIdx.x * 4 + (threadIdx.x >> 6);
    int lane = threadIdx.x & 63;
    int token = slot_token[s];
    int pos = slot_pos[s];
    const float4* px = (const float4*)(x + (size_t)token * Dc) + lane*4;
    float4 v0 = px[0], v1 = px[1], v2 = px[2], v3 = px[3];
    uint4 lo, hi;
    lo.x = pack2bf(v0.x, v0.y); lo.y = pack2bf(v0.z, v0.w);
    lo.z = pack2bf(v1.x, v1.y); lo.w = pack2bf(v1.z, v1.w);
    hi.x = pack2bf(v2.x, v2.y); hi.y = pack2bf(v2.z, v2.w);
    hi.z = pack2bf(v3.x, v3.y); hi.w = pack2bf(v3.z, v3.w);
    int kp = lane >> 1;
    int key = (pos >> 1) & 3;
    int c0 = (lane & 1) * 2;
    size_t base = (size_t)kp * PROWS + (size_t)s * 32;
    *(uint4*)&apk[base + ((c0 ^ key) * 8)]       = lo;
    *(uint4*)&apk[base + (((c0+1) ^ key) * 8)]   = hi;
}

// ---------------- GEMM1: HH = (X@W1+b1) * silu(X@W2+b2), per expert ----------------
// 128x128 cell, 4 waves, single acc/wave, 4 blocks/CU + 2-slot ring with counted vmcnt
// + raw barriers: DMA drain OFF the per-step critical path, co-residency preserved.
// 32KB LDS: A slots at 0/8KB, B slots at 16/24KB; epilogue sS aliases the whole buffer.
__global__ __launch_bounds__(256, 4) void k_gemm1(
    const unsigned short* __restrict__ apk,
    const unsigned short* __restrict__ w1p, const unsigned short* __restrict__ w2p,
    const float* __restrict__ b1, const float* __restrict__ b2,
    const int* __restrict__ counts, const int* __restrict__ offsets,
    unsigned short* __restrict__ hh2) {
    int e = blockIdx.z;
    int n_e = counts[e];
    int m0 = blockIdx.y * 128;
    if (m0 >= n_e) return;
    int base = offsets[e];
    int bx = blockIdx.x;                 // 64 x-blocks of 64 h-cols
    int n0 = bx * 64;
    int hp = bx >> 1, ro = (bx & 1) * 64;   // 128-panel + row offset inside it

    __shared__ __align__(16) unsigned char smem[32768];
    unsigned short* sU = (unsigned short*)smem;   // ushort view; A slot s: +s*4096, B slot s: +8192+s*4096
    float* sS = (float*)smem;                     // [128][64] epilogue silu exchange (aliases dbuf)

    int tid = threadIdx.x;
    int wid = tid >> 6, lane = tid & 63;
    int wr = wid >> 1, wc = wid & 1;

    // contiguous staging sources
    const unsigned short* aSrc = apk + (size_t)(base + m0 + wid*32)*32 + lane*8;   // + kk*PROWS
    const unsigned short* wmat = (wid < 2) ? w1p : w2p;
    const unsigned short* bSrc = wmat + ((size_t)(e*32 + hp) * 32) * 4096
                               + (size_t)(ro + (wid & 1)*32)*32 + lane*8;          // + kk*4096

    int arow = lane & 15, cr = lane >> 4;
    int ccf = cr ^ ((arow >> 1) & 3);
    int aoff[4], boff[4];
    #pragma unroll
    for (int m = 0; m < 4; m++) aoff[m] = (wr*64 + m*16 + arow)*32 + ccf*8;
    #pragma unroll
    for (int n = 0; n < 4; n++) boff[n] = 8192 + (wc*64 + n*16 + arow)*32 + ccf*8;

    f32x4 acc[4][4];
    #pragma unroll
    for (int m = 0; m < 4; m++)
        #pragma unroll
        for (int n = 0; n < 4; n++)
            #pragma unroll
            for (int j = 0; j < 4; j++) acc[m][n][j] = 0.0f;

    auto STAGE = [&](int s, int kk) {   // 4 loads per wave, contiguous 1KB each
        const unsigned short* a = aSrc + (size_t)kk*PROWS;
        const unsigned short* b = bSrc + (size_t)kk*4096;
        unsigned short* dA = sU + s*4096 + wid*1024;
        unsigned short* dB = sU + 8192 + s*4096 + wid*1024;
        gload16(a,       dA); gload16(a + 512, dA + 512);
        gload16(b,       dB); gload16(b + 512, dB + 512);
    };

    const int NK = Dc / 32;   // 32
    STAGE(0, 0); STAGE(1, 1);
    for (int kk = 0; kk < NK; ++kk) {
        int s = kk & 1;
        const unsigned short* sl = sU + s*4096;
        if (kk < NK - 1) { asm volatile("s_waitcnt vmcnt(4)" ::: "memory"); }
        else             { asm volatile("s_waitcnt vmcnt(0)" ::: "memory"); }
        fence_bar();                          // slot s published to all waves
        bf16x8 af[4], bf[4];
        #pragma unroll
        for (int m = 0; m < 4; m++) af[m] = *(const bf16x8*)&sl[aoff[m]];
        #pragma unroll
        for (int n = 0; n < 4; n++) bf[n] = *(const bf16x8*)&sl[boff[n]];
        #pragma unroll
        for (int m = 0; m < 4; m++)
            #pragma unroll
            for (int n = 0; n < 4; n++)
                acc[m][n] = __builtin_amdgcn_mfma_f32_16x16x32_bf16(af[m], bf[n], acc[m][n], 0, 0, 0);
        fence_bar();                          // all waves done reading slot s (WAR license)
        if (kk + 2 < NK) STAGE(s, kk + 2);    // refill slot s; waited at iter kk+2
    }

    // epilogue: wc=1 publish silu(h2) to LDS (XOR-swizzled cols: conflict-free); wc=0 multiply+store
    int lrow = (lane >> 4) * 4, lcol = lane & 15;
    if (wc == 1) {
        #pragma unroll
        for (int n = 0; n < 4; n++) {
            float b2v = b2[e*Hc + n0 + n*16 + lcol];
            #pragma unroll
            for (int m = 0; m < 4; m++) {
                int rb = wr*64 + m*16 + lrow;
                #pragma unroll
                for (int j = 0; j < 4; j++) {
                    float h2 = acc[m][n][j] + b2v;
                    sS[(rb + j)*64 + ((n*16 + lcol) ^ (j << 4))] = h2 / (1.0f + expf(-h2));
                }
            }
        }
    }
    __syncthreads();
    if (wc == 0) {
        #pragma unroll
        for (int n = 0; n < 4; n++) {
            int hcol = n0 + n*16 + lcol;
            float b1v = b1[e*Hc + hcol];
            int hp2 = hcol >> 5;
            int ch  = (hcol >> 3) & 3;
            int ho  = hcol & 7;
            #pragma unroll
            for (int m = 0; m < 4; m++) {
                int rb = wr*64 + m*16 + lrow;
                #pragma unroll
                for (int j = 0; j < 4; j++) {
                    int r = m0 + rb + j;
                    if (r < n_e) {
                        float v = (acc[m][n][j] + b1v) * sS[(rb + j)*64 + ((n*16 + lcol) ^ (j << 4))];
                        int key = (r >> 1) & 3;
                        hh2[(size_t)hp2 * PROWS + (size_t)(base + r)*32 + ((ch ^ key)*8) + ho] = f2bf(v);
                    }
                }
            }
        }
    }
}

// ---------------- GEMM2: OUT = HH @ Wp^T + bp, per expert ----------------
// Same cell: 128x128, 4 waves, 2-slot ring, counted vmcnt, 32KB LDS, 4 blocks/CU.
__global__ __launch_bounds__(256, 4) void k_gemm2(
    const unsigned short* __restrict__ hh2,
    const unsigned short* __restrict__ wpp,
    const float* __restrict__ bp,
    const int* __restrict__ counts, const int* __restrict__ offsets,
    float* __restrict__ outb) {
    int e = blockIdx.z;
    int n_e = counts[e];
    int m0 = blockIdx.y * 128;
    if (m0 >= n_e) return;
    int base = offsets[e];
    int dp = blockIdx.x;
    int n0 = dp * 128;

    __shared__ __align__(16) unsigned char smem[32768];
    unsigned short* sU = (unsigned short*)smem;   // A slot s: +s*4096, B slot s: +8192+s*4096

    int tid = threadIdx.x;
    int wid = tid >> 6, lane = tid & 63;
    int wr = wid >> 1, wc = wid & 1;

    const unsigned short* aSrc = hh2 + (size_t)(base + m0 + wid*32)*32 + lane*8;     // + kk*PROWS
    const unsigned short* bSrc = wpp + ((size_t)(e*8 + dp) * 128) * 4096
                               + wid*1024 + lane*8;                                   // + kk*4096

    int arow = lane & 15, cr = lane >> 4;
    int ccf = cr ^ ((arow >> 1) & 3);
    int aoff[4], boff[4];
    #pragma unroll
    for (int m = 0; m < 4; m++) aoff[m] = (wr*64 + m*16 + arow)*32 + ccf*8;
    #pragma unroll
    for (int n = 0; n < 4; n++) boff[n] = 8192 + (wc*64 + n*16 + arow)*32 + ccf*8;

    f32x4 acc[4][4];
    #pragma unroll
    for (int m = 0; m < 4; m++)
        #pragma unroll
        for (int n = 0; n < 4; n++)
            #pragma unroll
            for (int j = 0; j < 4; j++) acc[m][n][j] = 0.0f;

    auto STAGE = [&](int s, int kk) {
        const unsigned short* a = aSrc + (size_t)kk*PROWS;
        const unsigned short* b = bSrc + (size_t)kk*4096;
        unsigned short* dA = sU + s*4096 + wid*1024;
        unsigned short* dB = sU + 8192 + s*4096 + wid*1024;
        gload16(a,       dA); gload16(a + 512, dA + 512);
        gload16(b,       dB); gload16(b + 512, dB + 512);
    };

    const int NK = Hc / 32;   // 128
    STAGE(0, 0); STAGE(1, 1);
    for (int kk = 0; kk < NK; ++kk) {
        int s = kk & 1;
        const unsigned short* sl = sU + s*4096;
        if (kk < NK - 1) { asm volatile("s_waitcnt vmcnt(4)" ::: "memory"); }
        else             { asm volatile("s_waitcnt vmcnt(0)" ::: "memory"); }
        fence_bar();
        bf16x8 af[4], bf[4];
        #pragma unroll
        for (int m = 0; m < 4; m++) af[m] = *(const bf16x8*)&sl[aoff[m]];
        #pragma unroll
        for (int n = 0; n < 4; n++) bf[n] = *(const bf16x8*)&sl[boff[n]];
        #pragma unroll
        for (int m = 0; m < 4; m++)
            #pragma unroll
            for (int n = 0; n < 4; n++)
                acc[m][n] = __builtin_amdgcn_mfma_f32_16x16x32_bf16(af[m], bf[n], acc[m][n], 0, 0, 0);
        fence_bar();
        if (kk + 2 < NK) STAGE(s, kk + 2);
    }

    int lrow = (lane >> 4) * 4, lcol = lane & 15;
    #pragma unroll
    for (int n = 0; n < 4; n++) {
        int dcol = n0 + wc*64 + n*16 + lcol;
        float bias = bp[e*Dc + dcol];
        #pragma unroll
        for (int m = 0; m < 4; m++) {
            int rb2 = m0 + wr*64 + m*16 + lrow;
            #pragma unroll
            for (int j = 0; j < 4; j++) {
                int r = rb2 + j;
                if (r < n_e)
                    outb[(size_t)(base + r)*Dc + dcol] = acc[m][n][j] + bias;
            }
        }
    }
}

// ---------------- combine: final[t] = w0*OUT[s0] + w1*OUT[s1] ----------------
__global__ void k_combine(const float* __restrict__ outb, const int* __restrict__ slot_of,
                          const float* __restrict__ tok_w, float* __restrict__ final_out) {
    int gid = blockIdx.x * 256 + threadIdx.x;   // Tc*Dc/4 threads
    int t = gid >> 8;
    int c = (gid & 255) * 4;
    int s0 = slot_of[t*2], s1 = slot_of[t*2 + 1];
    float w0 = tok_w[t*2], w1 = tok_w[t*2 + 1];
    float4 o0 = *(const float4*)&outb[(size_t)s0*Dc + c];
    float4 o1 = *(const float4*)&outb[(size_t)s1*Dc + c];
    float4 r;
    r.x = w0*o0.x + w1*o1.x;
    r.y = w0*o0.y + w1*o1.y;
    r.z = w0*o0.z + w1*o1.z;
    r.w = w0*o0.w + w1*o1.w;
    *(float4*)&final_out[(size_t)t*Dc + c] = r;
}

extern "C" void kernel_launch(void* const* d_in, const int* in_sizes, int n_in,
                              void* d_out, int out_size, void* d_ws, size_t ws_size,
                              hipStream_t stream) {
    (void)in_sizes; (void)n_in; (void)out_size; (void)ws_size;
    const float* x     = (const float*)d_in[0];
    const float* noise = (const float*)d_in[1];
    const float* Wg    = (const float*)d_in[2];
    const float* nw    = (const float*)d_in[3];
    const float* W1    = (const float*)d_in[4];
    const float* b1    = (const float*)d_in[5];
    const float* W2    = (const float*)d_in[6];
    const float* b2    = (const float*)d_in[7];
    const float* Wp    = (const float*)d_in[8];
    const float* bp    = (const float*)d_in[9];

    char* ws = (char*)d_ws;
    size_t off = 0;
    unsigned short* W1P = (unsigned short*)(ws + off); off += (size_t)Ec*Dc*Hc*2;      // 64 MB
    unsigned short* W2P = (unsigned short*)(ws + off); off += (size_t)Ec*Dc*Hc*2;      // 64 MB
    unsigned short* WPP = (unsigned short*)(ws + off); off += (size_t)Ec*Hc*Dc*2;      // 64 MB
    unsigned short* APK = (unsigned short*)(ws + off); off += (size_t)32*PROWS*2;      // 16.5 MB
    unsigned short* HH2 = (unsigned short*)(ws + off); off += (size_t)128*PROWS*2;     // 66 MB
    float*          OUTB= (float*)(ws + off);          off += (size_t)NSLOT*Dc*4;      // 32 MB
    int*   counts    = (int*)(ws + off);
    int*   fill      = (int*)(ws + off + 32);
    int*   offsets   = (int*)(ws + off + 64);
    int*   tok_top   = (int*)(ws + off + 128);
    float* tok_w     = (float*)(ws + off + 128 + (size_t)Tc*2*4);
    int*   slot_token= (int*)(ws + off + 128 + (size_t)Tc*2*8);
    int*   slot_of   = (int*)(ws + off + 128 + (size_t)Tc*2*8 + (size_t)NSLOT*4);
    int*   slot_pos  = (int*)(ws + off + 128 + (size_t)Tc*2*8 + (size_t)NSLOT*8);

    float* final_out = (float*)d_out;
    float* idx_out   = (float*)d_out + FINAL_N;

    (void)hipMemsetAsync(counts, 0, 64, stream);   // counts + fill

    // W1 + W2 panel transposes in one launch (z = 16: [0,8) -> W1, [8,16) -> W2)
    k_transpose_panel<<<dim3(Hc/64, Dc/64, 2*Ec), 256, 0, stream>>>(W1, W2, W1P, W2P, Dc, Hc, Ec);
    k_transpose_panel<<<dim3(Dc/64, Hc/64, Ec), 256, 0, stream>>>(Wp, Wp, WPP, WPP, Hc, Dc, Ec);

    k_gate<<<Tc, 64, 0, stream>>>(x, noise, Wg, nw, idx_out, counts, tok_top, tok_w);
    k_scan<<<1, 64, 0, stream>>>(counts, offsets);
    k_fill<<<Tc/256, 256, 0, stream>>>(tok_top, offsets, fill, slot_token, slot_of, slot_pos);
    k_packA<<<NSLOT/4, 256, 0, stream>>>(x, slot_token, slot_pos, APK);

    k_gemm1<<<dim3(Hc/64, Tc/128, Ec), 256, 0, stream>>>(APK, W1P, W2P, b1, b2,
                                                         counts, offsets, HH2);
    k_gemm2<<<dim3(Dc/128, Tc/128, Ec), 256, 0, stream>>>(HH2, WPP, bp, counts, offsets, OUTB);
    k_combine<<<(Tc*Dc/4)/256, 256, 0, stream>>>(OUTB, slot_of, tok_w, final_out);
}